// Round 1
// baseline (1791.499 us; speedup 1.0000x reference)
//
#include <hip/hip_runtime.h>

constexpr int B = 64, A = 1024, E = 2048, NB = 10, H = 128, FA = 82;
constexpr int M = B * A;  // 65536 rows

// ---------------------------------------------------------------------------
// Generic row-matmul: C[m][h] (=|+=) A[m][0:K] @ W[K][H] (+ bias[h])
// KOUT epilogue: C[o] = v * FN[o] * nmask[m]   (kernel = f_self*f_nei*node_mask)
// Weight stationary in LDS; rows read with block-uniform addresses (scalar
// loads); each thread computes 4 rows to reuse each W element 4x.
// ---------------------------------------------------------------------------
template<int K, bool ACC, bool BIAS, bool KOUT>
__global__ __launch_bounds__(256) void gemm_rows(
    const float* __restrict__ Ain, const float* __restrict__ W,
    const float* __restrict__ bias, float* __restrict__ C,
    const float* __restrict__ FN, const float* __restrict__ nmask)
{
    __shared__ float sW[K * H];
    for (int i = threadIdx.x; i < K * H; i += 256) sW[i] = W[i];
    __syncthreads();

    const int h   = threadIdx.x & 127;
    const int sub = threadIdx.x >> 7;          // 0/1: which 4-row group
    const int nchunk = M / 8;

    for (int c = blockIdx.x; c < nchunk; c += gridDim.x) {
        const int m0 = c * 8 + sub * 4;
        const float* a0 = Ain + (size_t)m0 * K;
        float acc0 = 0.f, acc1 = 0.f, acc2 = 0.f, acc3 = 0.f;
        #pragma unroll 8
        for (int k = 0; k < K; ++k) {
            const float w = sW[k * H + h];      // bank = h%32 -> 2-way, free
            acc0 += a0[k]         * w;          // block-uniform -> s_load
            acc1 += a0[K + k]     * w;
            acc2 += a0[2 * K + k] * w;
            acc3 += a0[3 * K + k] * w;
        }
        float accs[4] = {acc0, acc1, acc2, acc3};
        #pragma unroll
        for (int r = 0; r < 4; ++r) {
            const int m = m0 + r;
            const size_t o = (size_t)m * H + h;
            float v = accs[r];
            if (BIAS) v += bias[h];
            if (KOUT)     C[o] = v * FN[o] * nmask[m];
            else if (ACC) C[o] += v;
            else          C[o] = v;
        }
    }
}

// ---------------------------------------------------------------------------
// Neighbor gather: SATOM[m][h] = sum_{nb<nnb} AF[b, ag[m,nb]][h]
// If CF: FNEI[m][h] = sum_{nb<nnb} ATW[b, ag[m,nb]][h] * (bond[b, bg[m,nb]] @ Wnb)[h]
// ---------------------------------------------------------------------------
template<bool CF>
__global__ __launch_bounds__(256) void gather_nei(
    const float* __restrict__ AF, const float* __restrict__ ATW,
    const float* __restrict__ bond, const int* __restrict__ ag,
    const int* __restrict__ bg, const int* __restrict__ nn,
    const float* __restrict__ Wnb, float* __restrict__ SATOM,
    float* __restrict__ FNEI)
{
    __shared__ float sWnb[6 * H];
    if (CF) {
        for (int i = threadIdx.x; i < 6 * H; i += 256) sWnb[i] = Wnb[i];
        __syncthreads();
    }
    const int h   = threadIdx.x & 127;
    const int sub = threadIdx.x >> 7;

    for (int m = blockIdx.x * 2 + sub; m < M; m += gridDim.x * 2) {
        const int b = m >> 10;                 // A = 1024
        const int nnb = nn[m];
        const size_t bbase = (size_t)(b) << 10;
        float s = 0.f, fn = 0.f;
        for (int nb = 0; nb < nnb; ++nb) {
            const int ia = ag[m * NB + nb];
            const size_t ra = (bbase + (size_t)ia) * H + h;
            s += AF[ra];
            if (CF) {
                const int ib = bg[m * NB + nb];
                const float* fb = bond + ((size_t)(b << 11) + (size_t)ib) * 6;  // E=2048
                float hnb = 0.f;
                #pragma unroll
                for (int j = 0; j < 6; ++j) hnb += fb[j] * sWnb[j * H + h];
                fn += ATW[ra] * hnb;
            }
        }
        const size_t o = (size_t)m * H + h;
        SATOM[o] = s;
        if (CF) FNEI[o] = fn;
    }
}

// ---------------------------------------------------------------------------
// One-time prep:
//  W2[8][128]: rows 0..5 = W_U2[128+j][:], row 6 = b_U2, row 7 = 0
//  FBS8[m][8]: [ sum_nb bond[bg[m,nb]][0..5], (float)num_nbs, 0 ]
//  (so nei_label = SATOM@W_U2a + FBS8@W2 exactly reproduces the masked U2 sum)
// ---------------------------------------------------------------------------
__global__ __launch_bounds__(256) void prep_w2_fbs(
    const float* __restrict__ WU2, const float* __restrict__ bU2,
    const float* __restrict__ bond, const int* __restrict__ bg,
    const int* __restrict__ nn, float* __restrict__ W2, float* __restrict__ FBS8)
{
    const int tid = blockIdx.x * 256 + threadIdx.x;
    if (tid < 8 * H) {
        const int j = tid >> 7, hh = tid & 127;
        W2[tid] = (j < 6) ? WU2[(128 + j) * H + hh] : ((j == 6) ? bU2[hh] : 0.f);
    }
    for (int m = tid; m < M; m += gridDim.x * 256) {
        const int b = m >> 10;
        const int nnb = nn[m];
        float s0 = 0, s1 = 0, s2 = 0, s3 = 0, s4 = 0, s5 = 0;
        for (int nb = 0; nb < nnb; ++nb) {
            const int ib = bg[m * NB + nb];
            const float* fb = bond + ((size_t)(b << 11) + (size_t)ib) * 6;
            s0 += fb[0]; s1 += fb[1]; s2 += fb[2];
            s3 += fb[3]; s4 += fb[4]; s5 += fb[5];
        }
        float* o = FBS8 + (size_t)m * 8;
        o[0] = s0; o[1] = s1; o[2] = s2; o[3] = s3; o[4] = s4; o[5] = s5;
        o[6] = (float)nnb; o[7] = 0.f;
    }
}

// ---------------------------------------------------------------------------
extern "C" void kernel_launch(void* const* d_in, const int* in_sizes, int n_in,
                              void* d_out, int out_size, void* d_ws, size_t ws_size,
                              hipStream_t stream)
{
    (void)in_sizes; (void)n_in; (void)out_size; (void)ws_size;

    const float* input_atom = (const float*)d_in[0];
    const float* input_bond = (const float*)d_in[1];
    const int*   atom_graph = (const int*)d_in[2];
    const int*   bond_graph = (const int*)d_in[3];
    const int*   num_nbs    = (const int*)d_in[4];
    const float* node_mask  = (const float*)d_in[5];
    const float* W_atom     = (const float*)d_in[6];
    const float* W_nei_atom = (const float*)d_in[7];
    const float* W_nei_bond = (const float*)d_in[8];
    const float* W_self     = (const float*)d_in[9];
    const float* W_U2       = (const float*)d_in[10];
    const float* b_U2       = (const float*)d_in[11];
    const float* W_U1       = (const float*)d_in[12];
    const float* b_U1       = (const float*)d_in[13];

    const size_t SL = (size_t)M * H;           // 8,388,608 floats = 32 MB
    float* ws    = (float*)d_ws;
    float* buf0  = ws;                         // atom_features ping
    float* buf1  = ws + SL;                    // atom_features pong / ATW / NLBL(last)
    float* FBS8  = ws + 2 * SL;                // 65536 x 8
    float* W2    = FBS8 + (size_t)M * 8;       // 8 x 128
    // total ws use: 2*32MB + 2MB + 4KB ~= 66 MB

    float* out0 = (float*)d_out;               // kernel output  [M,H]
    float* out1 = out0 + SL;                   // atom_features  [M,H]

    const float* W_U1a = W_U1;                 // rows 0..127
    const float* W_U1b = W_U1 + 128 * H;       // rows 128..255

    prep_w2_fbs<<<256, 256, 0, stream>>>(W_U2, b_U2, input_bond, bond_graph,
                                         num_nbs, W2, FBS8);
    // AF = input_atom @ W_atom
    gemm_rows<FA, false, false, false><<<2048, 256, 0, stream>>>(
        input_atom, W_atom, nullptr, buf0, nullptr, nullptr);

    float* AF  = buf0;
    float* AFn = buf1;
    for (int d = 0; d < 3; ++d) {
        const bool last = (d == 2);
        if (last) {
            // ATW = AF @ W_nei_atom  -> buf1 (free at last depth)
            gemm_rows<H, false, false, false><<<2048, 256, 0, stream>>>(
                AF, W_nei_atom, nullptr, buf1, nullptr, nullptr);
            // SATOM -> out1 (scratch), FNEI -> out0 (scratch)
            gather_nei<true><<<8192, 256, 0, stream>>>(
                AF, buf1, input_bond, atom_graph, bond_graph, num_nbs,
                W_nei_bond, out1, out0);
            // kernel = (AF@W_self) * FNEI * node_mask  -> out0 (final)
            gemm_rows<H, false, false, true><<<2048, 256, 0, stream>>>(
                AF, W_self, nullptr, out0, out0, node_mask);
            // NLBL = SATOM@W_U2a + FBS8@W2 -> buf1 (ATW dead now)
            gemm_rows<H, false, false, false><<<2048, 256, 0, stream>>>(
                out1, W_U2, nullptr, buf1, nullptr, nullptr);
            gemm_rows<8, true, false, false><<<2048, 256, 0, stream>>>(
                FBS8, W2, nullptr, buf1, nullptr, nullptr);
            // atom_features = AF@W_U1a + NLBL@W_U1b + b_U1 -> out1 (final)
            gemm_rows<H, false, true, false><<<2048, 256, 0, stream>>>(
                AF, W_U1a, b_U1, out1, nullptr, nullptr);
            gemm_rows<H, true, false, false><<<2048, 256, 0, stream>>>(
                buf1, W_U1b, nullptr, out1, nullptr, nullptr);
        } else {
            // SATOM -> out1 (scratch; d_out is ours until the end)
            gather_nei<false><<<8192, 256, 0, stream>>>(
                AF, nullptr, input_bond, atom_graph, bond_graph, num_nbs,
                W_nei_bond, out1, nullptr);
            // NLBL = SATOM@W_U2a + FBS8@W2 -> out0 (scratch)
            gemm_rows<H, false, false, false><<<2048, 256, 0, stream>>>(
                out1, W_U2, nullptr, out0, nullptr, nullptr);
            gemm_rows<8, true, false, false><<<2048, 256, 0, stream>>>(
                FBS8, W2, nullptr, out0, nullptr, nullptr);
            // AF_next = AF@W_U1a + NLBL@W_U1b + b_U1
            gemm_rows<H, false, true, false><<<2048, 256, 0, stream>>>(
                AF, W_U1a, b_U1, AFn, nullptr, nullptr);
            gemm_rows<H, true, false, false><<<2048, 256, 0, stream>>>(
                out0, W_U1b, nullptr, AFn, nullptr, nullptr);
            float* t = AF; AF = AFn; AFn = t;
        }
    }
}

// Round 2
// 305.744 us; speedup vs baseline: 5.8595x; 5.8595x over previous
//
#include <hip/hip_runtime.h>

constexpr int B = 64, A = 1024, E = 2048, NB = 10, H = 128;
constexpr int M = B * A;                 // 65536 rows
constexpr long SL = (long)M * H;         // 8388608 elems per [M,H] matrix

typedef __attribute__((ext_vector_type(8))) short s16x8;
typedef __attribute__((ext_vector_type(4))) float f32x4;

__device__ __forceinline__ ushort f2b(float f) {
    union { float f; uint u; } v; v.f = f;
    uint u = v.u;
    uint r = u + 0x7fffu + ((u >> 16) & 1u);
    return (ushort)(r >> 16);
}
__device__ __forceinline__ float b2f(ushort u) {
    union { uint u; float f; } v; v.u = ((uint)u) << 16; return v.f;
}

// ---------------------------------------------------------------------------
// MFMA row-GEMM: C[M][128] = A[M][K=NC*32](bf16) @ W[K][128]
// WT is W transposed: [128][K] bf16, so B-frags are contiguous short8 loads.
// Whole B operand resident in registers per wave (8 coltiles x NC frags).
// FLAGS: 1=FBS (add FBS8[M][8] @ W2 via padded K=32 chunk), 2=ADDP (+= P f32),
//        4=BIAS (+ bias f32), 8=KOUT (v *= FN*nmask), 16=OUTF32
// ---------------------------------------------------------------------------
template<int NC, int FLAGS>
__global__ __launch_bounds__(256, 1) void gemm_mf(
    const ushort* __restrict__ Abf, const ushort* __restrict__ WT,
    const ushort* __restrict__ FBSb, const ushort* __restrict__ WT2,
    const float* __restrict__ P, const float* __restrict__ bias,
    const float* __restrict__ FN, const float* __restrict__ nmask,
    float* __restrict__ Cf, ushort* __restrict__ Cb)
{
    constexpr bool FBS  = FLAGS & 1, ADDP = FLAGS & 2, BIAS = FLAGS & 4;
    constexpr bool KOUT = FLAGS & 8, OF32 = FLAGS & 16;
    constexpr int K = NC * 32;

    const int lane = threadIdx.x & 63;
    const int wid  = threadIdx.x >> 6;
    const int l15  = lane & 15, g = lane >> 4;

    // resident B fragments
    s16x8 bfr[8][NC];
    #pragma unroll
    for (int c = 0; c < 8; ++c)
        #pragma unroll
        for (int kc = 0; kc < NC; ++kc)
            bfr[c][kc] = *(const s16x8*)(WT + (size_t)(c * 16 + l15) * K + kc * 32 + g * 8);
    s16x8 b2r[8];
    if constexpr (FBS) {
        #pragma unroll
        for (int c = 0; c < 8; ++c)
            b2r[c] = *(const s16x8*)(WT2 + (size_t)(c * 16 + l15) * 32 + g * 8);
    }

    const int nwaves = gridDim.x * 4;
    for (int t = blockIdx.x * 4 + wid; t < M / 16; t += nwaves) {
        const int m0 = t * 16;
        const size_t abase = (size_t)(m0 + l15) * K + g * 8;
        s16x8 afr[NC];
        #pragma unroll
        for (int kc = 0; kc < NC; ++kc)
            afr[kc] = *(const s16x8*)(Abf + abase + kc * 32);

        f32x4 acc[8];
        #pragma unroll
        for (int c = 0; c < 8; ++c) acc[c] = (f32x4){0.f, 0.f, 0.f, 0.f};
        #pragma unroll
        for (int kc = 0; kc < NC; ++kc)
            #pragma unroll
            for (int c = 0; c < 8; ++c)
                acc[c] = __builtin_amdgcn_mfma_f32_16x16x32_bf16(afr[kc], bfr[c][kc], acc[c], 0, 0, 0);
        if constexpr (FBS) {
            s16x8 af = (s16x8){0,0,0,0,0,0,0,0};
            if (g == 0) af = *(const s16x8*)(FBSb + (size_t)(m0 + l15) * 8);
            #pragma unroll
            for (int c = 0; c < 8; ++c)
                acc[c] = __builtin_amdgcn_mfma_f32_16x16x32_bf16(af, b2r[c], acc[c], 0, 0, 0);
        }

        // epilogue: D col = lane&15, row = 4*(lane>>4)+reg  [m89-verified]
        #pragma unroll
        for (int c = 0; c < 8; ++c) {
            const int col = c * 16 + l15;
            float bc = 0.f;
            if constexpr (BIAS) bc = bias[col];
            #pragma unroll
            for (int r = 0; r < 4; ++r) {
                const int m = m0 + 4 * g + r;
                const size_t o = (size_t)m * H + col;
                float v = acc[c][r];
                if constexpr (BIAS) v += bc;
                if constexpr (ADDP) v += P[o];
                if constexpr (KOUT) v = v * FN[o] * nmask[m];
                if constexpr (OF32) Cf[o] = v; else Cb[o] = f2b(v);
            }
        }
    }
}

// ---------------------------------------------------------------------------
// Gather: SATOM[m][:] = sum_{nb<nnb} AF[b, ag[m,nb]][:]        (bf16 out)
// CF: FNEI[m][:] = sum_nb ATW[b, ag[m,nb]][:] * (bond[bg] @ Wnb)[:]  (f32 out)
// 16 threads per row, 8 cols each (16B vector loads).
// ---------------------------------------------------------------------------
template<bool CF>
__global__ __launch_bounds__(256) void gather_nei(
    const ushort* __restrict__ AF, const ushort* __restrict__ ATW,
    const float* __restrict__ bond, const int* __restrict__ ag,
    const int* __restrict__ bg, const int* __restrict__ nn,
    const float* __restrict__ Wnb, ushort* __restrict__ SATOM,
    float* __restrict__ FNEI)
{
    const int m  = blockIdx.x * 16 + (threadIdx.x >> 4);
    const int c8 = (threadIdx.x & 15) * 8;
    const int b  = m >> 10;
    const int nnb = nn[m];

    float WnbR[6][8];
    if constexpr (CF) {
        #pragma unroll
        for (int j = 0; j < 6; ++j)
            #pragma unroll
            for (int i = 0; i < 8; ++i) WnbR[j][i] = Wnb[j * H + c8 + i];
    }
    float sacc[8] = {0,0,0,0,0,0,0,0}, facc[8] = {0,0,0,0,0,0,0,0};

    for (int nb = 0; nb < nnb; ++nb) {
        const int ia = ag[m * NB + nb];
        const size_t ra = ((size_t)(b << 10) + (size_t)ia) * H + c8;
        s16x8 av = *(const s16x8*)(AF + ra);
        #pragma unroll
        for (int i = 0; i < 8; ++i) sacc[i] += b2f((ushort)av[i]);
        if constexpr (CF) {
            const int ib = bg[m * NB + nb];
            const float* fb = bond + ((size_t)(b << 11) + (size_t)ib) * 6;
            const float f0 = fb[0], f1 = fb[1], f2 = fb[2], f3 = fb[3], f4 = fb[4], f5 = fb[5];
            s16x8 tv = *(const s16x8*)(ATW + ra);
            #pragma unroll
            for (int i = 0; i < 8; ++i) {
                const float hnb = f0*WnbR[0][i] + f1*WnbR[1][i] + f2*WnbR[2][i]
                                + f3*WnbR[3][i] + f4*WnbR[4][i] + f5*WnbR[5][i];
                facc[i] += b2f((ushort)tv[i]) * hnb;
            }
        }
    }
    s16x8 so;
    #pragma unroll
    for (int i = 0; i < 8; ++i) so[i] = (short)f2b(sacc[i]);
    *(s16x8*)(SATOM + (size_t)m * H + c8) = so;
    if constexpr (CF) {
        f32x4 lo = {facc[0], facc[1], facc[2], facc[3]};
        f32x4 hi = {facc[4], facc[5], facc[6], facc[7]};
        *(f32x4*)(FNEI + (size_t)m * H + c8)     = lo;
        *(f32x4*)(FNEI + (size_t)m * H + c8 + 4) = hi;
    }
}

// FBS8[m][8] = bf16[ sum_nb bond[bg[m,nb]][0..5], num_nbs, 0 ]
__global__ __launch_bounds__(256) void prep_fbs(
    const float* __restrict__ bond, const int* __restrict__ bg,
    const int* __restrict__ nn, ushort* __restrict__ FBSb)
{
    const int m = blockIdx.x * 256 + threadIdx.x;
    const int b = m >> 10;
    const int nnb = nn[m];
    float s[6] = {0,0,0,0,0,0};
    for (int nb = 0; nb < nnb; ++nb) {
        const int ib = bg[m * NB + nb];
        const float* fb = bond + ((size_t)(b << 11) + (size_t)ib) * 6;
        #pragma unroll
        for (int j = 0; j < 6; ++j) s[j] += fb[j];
    }
    s16x8 o;
    #pragma unroll
    for (int j = 0; j < 6; ++j) o[j] = (short)f2b(s[j]);
    o[6] = (short)f2b((float)nnb);
    o[7] = 0;
    *(s16x8*)(FBSb + (size_t)m * 8) = o;
}

// input_atom [M][82] f32 -> [M][96] bf16 (zero-padded)
__global__ __launch_bounds__(256) void cvt_atom(
    const float* __restrict__ ia, ushort* __restrict__ out)
{
    const int tid = blockIdx.x * 256 + threadIdx.x;   // M*12
    const int m = tid / 12, c = (tid % 12) * 8;
    s16x8 v;
    #pragma unroll
    for (int i = 0; i < 8; ++i) {
        const int k = c + i;
        v[i] = (short)(k < 82 ? f2b(ia[(size_t)m * 82 + k]) : 0);
    }
    *(s16x8*)(out + (size_t)m * 96 + c) = v;
}

// Transposed bf16 weights, concatenated:
// WTa[128][96] | WTna[128][128] | WTs[128][128] | WTu2a[128][128]
// | WTu1a[128][128] | WTu1b[128][128] | WT2p[128][32]
__global__ __launch_bounds__(256) void prep_w(
    const float* __restrict__ Wa, const float* __restrict__ Wna,
    const float* __restrict__ Ws, const float* __restrict__ Wu2,
    const float* __restrict__ bu2, const float* __restrict__ Wu1,
    ushort* __restrict__ out)
{
    int t = blockIdx.x * 256 + threadIdx.x;
    const int tid = t;
    if (t < 128 * 96) { int n = t / 96, k = t % 96;
        out[tid] = (k < 82) ? f2b(Wa[k * H + n]) : 0; return; }
    t -= 128 * 96;
    if (t < 128 * 128) { int n = t / 128, k = t % 128;
        out[tid] = f2b(Wna[k * H + n]); return; }
    t -= 128 * 128;
    if (t < 128 * 128) { int n = t / 128, k = t % 128;
        out[tid] = f2b(Ws[k * H + n]); return; }
    t -= 128 * 128;
    if (t < 128 * 128) { int n = t / 128, k = t % 128;
        out[tid] = f2b(Wu2[k * H + n]); return; }
    t -= 128 * 128;
    if (t < 128 * 128) { int n = t / 128, k = t % 128;
        out[tid] = f2b(Wu1[k * H + n]); return; }
    t -= 128 * 128;
    if (t < 128 * 128) { int n = t / 128, k = t % 128;
        out[tid] = f2b(Wu1[(128 + k) * H + n]); return; }
    t -= 128 * 128;
    if (t < 128 * 32) { int n = t / 32, j = t % 32;
        ushort v = 0;
        if (j < 6) v = f2b(Wu2[(128 + j) * H + n]);
        else if (j == 6) v = f2b(bu2[n]);
        out[tid] = v; return; }
}

// ---------------------------------------------------------------------------
extern "C" void kernel_launch(void* const* d_in, const int* in_sizes, int n_in,
                              void* d_out, int out_size, void* d_ws, size_t ws_size,
                              hipStream_t stream)
{
    (void)in_sizes; (void)n_in; (void)out_size; (void)ws_size;

    const float* input_atom = (const float*)d_in[0];
    const float* input_bond = (const float*)d_in[1];
    const int*   atom_graph = (const int*)d_in[2];
    const int*   bond_graph = (const int*)d_in[3];
    const int*   num_nbs    = (const int*)d_in[4];
    const float* node_mask  = (const float*)d_in[5];
    const float* W_atom     = (const float*)d_in[6];
    const float* W_nei_atom = (const float*)d_in[7];
    const float* W_nei_bond = (const float*)d_in[8];
    const float* W_self     = (const float*)d_in[9];
    const float* W_U2       = (const float*)d_in[10];
    const float* b_U2       = (const float*)d_in[11];
    const float* W_U1       = (const float*)d_in[12];
    const float* b_U1       = (const float*)d_in[13];

    char* ws = (char*)d_ws;
    ushort* AF0  = (ushort*)(ws);                       // 16 MB bf16 [M][128]
    ushort* AF1  = (ushort*)(ws + (SL * 2));            // 16 MB
    ushort* NLBL = (ushort*)(ws + (SL * 4));            // 16 MB
    float*  Pbuf = (float*) (ws + (SL * 6));            // 32 MB f32 [M][128]
    ushort* AFin = (ushort*)(ws + (SL * 6));            //   (12 MB, dead after FA)
    ushort* ATW  = (ushort*)(ws + (SL * 6));            //   (16 MB, dead before P write)
    ushort* FBSb = (ushort*)(ws + (SL * 10));           // 1 MB bf16 [M][8]
    ushort* WTs_ = (ushort*)(ws + (SL * 10) + M * 8 * 2);

    ushort* WTa   = WTs_;                 // [128][96]
    ushort* WTna  = WTa  + 128 * 96;      // [128][128]
    ushort* WTslf = WTna + 128 * 128;
    ushort* WTu2a = WTslf + 128 * 128;
    ushort* WTu1a = WTu2a + 128 * 128;
    ushort* WTu1b = WTu1a + 128 * 128;
    ushort* WT2p  = WTu1b + 128 * 128;    // [128][32]

    float*  out0  = (float*)d_out;        // kernel [M][128] f32
    float*  out1  = out0 + SL;            // atom_features [M][128] f32
    ushort* SATOM = (ushort*)out0;        // scratch bf16 (overwritten by KOUT)
    float*  FNEI  = out1;                 // scratch f32 (overwritten by final U1b)

    prep_w<<<384, 256, 0, stream>>>(W_atom, W_nei_atom, W_self, W_U2, b_U2, W_U1, WTs_);
    cvt_atom<<<M * 12 / 256, 256, 0, stream>>>(input_atom, AFin);
    prep_fbs<<<M / 256, 256, 0, stream>>>(input_bond, bond_graph, num_nbs, FBSb);

    // AF0 = input_atom @ W_atom   (K=96 padded)
    gemm_mf<3, 0><<<512, 256, 0, stream>>>(AFin, WTa, nullptr, nullptr, nullptr,
                                           nullptr, nullptr, nullptr, nullptr, AF0);

    ushort* AF  = AF0;
    ushort* AFn = AF1;
    for (int d = 0; d < 2; ++d) {
        gather_nei<false><<<M / 16, 256, 0, stream>>>(
            AF, nullptr, input_bond, atom_graph, bond_graph, num_nbs,
            nullptr, SATOM, nullptr);
        // NLBL = SATOM @ W_U2a + FBS8 @ W2
        gemm_mf<4, 1><<<512, 256, 0, stream>>>(SATOM, WTu2a, FBSb, WT2p, nullptr,
                                               nullptr, nullptr, nullptr, nullptr, NLBL);
        // P = AF @ W_U1a
        gemm_mf<4, 16><<<512, 256, 0, stream>>>(AF, WTu1a, nullptr, nullptr, nullptr,
                                                nullptr, nullptr, nullptr, Pbuf, nullptr);
        // AF_next = P + NLBL @ W_U1b + b_U1
        gemm_mf<4, 2 | 4><<<512, 256, 0, stream>>>(NLBL, WTu1b, nullptr, nullptr, Pbuf,
                                                   b_U1, nullptr, nullptr, nullptr, AFn);
        ushort* tmp = AF; AF = AFn; AFn = tmp;
    }

    // ---- last depth ----
    // ATW = AF @ W_nei_atom
    gemm_mf<4, 0><<<512, 256, 0, stream>>>(AF, WTna, nullptr, nullptr, nullptr,
                                           nullptr, nullptr, nullptr, nullptr, ATW);
    gather_nei<true><<<M / 16, 256, 0, stream>>>(
        AF, ATW, input_bond, atom_graph, bond_graph, num_nbs,
        W_nei_bond, SATOM, FNEI);
    // NLBL = SATOM @ W_U2a + FBS8 @ W2   (must read SATOM=out0 before KOUT writes)
    gemm_mf<4, 1><<<512, 256, 0, stream>>>(SATOM, WTu2a, FBSb, WT2p, nullptr,
                                           nullptr, nullptr, nullptr, nullptr, NLBL);
    // P = AF @ W_U1a   (overwrites ATW region — ATW is dead now)
    gemm_mf<4, 16><<<512, 256, 0, stream>>>(AF, WTu1a, nullptr, nullptr, nullptr,
                                            nullptr, nullptr, nullptr, Pbuf, nullptr);
    // kernel = (AF @ W_self) * FNEI * node_mask  -> out0 (reads FNEI=out1 first)
    gemm_mf<4, 8 | 16><<<512, 256, 0, stream>>>(AF, WTslf, nullptr, nullptr, nullptr,
                                                nullptr, FNEI, node_mask, out0, nullptr);
    // atom_features = P + NLBL @ W_U1b + b_U1 -> out1 (f32, overwrites FNEI)
    gemm_mf<4, 2 | 4 | 16><<<512, 256, 0, stream>>>(NLBL, WTu1b, nullptr, nullptr, Pbuf,
                                                    b_U1, nullptr, nullptr, out1, nullptr);
}